// Round 3
// baseline (580.441 us; speedup 1.0000x reference)
//
#include <hip/hip_runtime.h>
#include <hip/hip_fp16.h>
#include <math.h>

// ---------------------------------------------------------------------------
// SimSiam head loss, 12 heads, fp32 in, B=8 H=512 W=768 -> per head (8,3,512,256)
//
// R5 structure: 4 dispatches total (was 8). No cooperative launch (R4 hung:
// graph-captured cooperative kernels lose co-residency -> grid.sync deadlock).
//   pass1: read fp32 x -> x 9-moments (P0), write fp16(x) (151 MB ws), zero loss
//   pass2: per-block fold bn1 from P0; read fp16 x -> a; 9-moments(a) -> P1
//   pass3: per-block fold bn1,bn2; read fp16 x -> a -> a2; 9-moments(a2) -> P2
//          (READ-ONLY: a2 is not stored; pass4 recomputes it)
//   pass4: per-block fold bn1,bn2,bn3,bn4; read fp16 x both latents; full chain
//          x->a->a2->z->p; cosine loss; atomicAdd(double); last block finalizes.
// Stats/finalize kernels are gone: each block derives its slice's folded BN
// params by reducing the 128x9-double partial array itself (~9 KB from L2).
// ws traffic: 151w + 3*151r (all read-only after pass1). Fallback (small ws):
// same 4 kernels re-reading fp32 x.
// ---------------------------------------------------------------------------

typedef unsigned short ushort_t;
typedef unsigned int   uint_t;

constexpr int   NH      = 12;
constexpr int   POS     = 131072;               // floats per channel per (b,head)
constexpr int   NB      = 8;
constexpr long long MLL = (long long)NB * POS;  // 1,048,576 positions per slice
constexpr int   CSPAN   = POS / 16;             // 8192 floats/channel per block
constexpr int   SBLK    = 128;                  // blocks per slice = 8 b * 16 x
constexpr int   NTOT    = NB * NH * 3 * POS;    // 37,748,736 elements per latent

constexpr size_t P_CNT      = (size_t)24 * SBLK * 9;   // doubles per P array
constexpr size_t NEED_BYTES = (size_t)NTOT * 2 * 2 + 3 * P_CNT * 8 + 64;

// ---------------- block reduction: 256 threads -> thread 0 ----------------
// Leading __syncthreads makes repeated calls safe (shared-buffer reuse).
template <int K>
__device__ inline void block_reduce_to0(double (&v)[K]) {
#pragma unroll
  for (int off = 32; off > 0; off >>= 1) {
#pragma unroll
    for (int k = 0; k < K; ++k) v[k] += __shfl_down(v[k], off, 64);
  }
  __shared__ double lds[4][K];
  __syncthreads();
  const int lane = threadIdx.x & 63;
  const int wv   = threadIdx.x >> 6;
  if (lane == 0) {
#pragma unroll
    for (int k = 0; k < K; ++k) lds[wv][k] = v[k];
  }
  __syncthreads();
  if (threadIdx.x == 0) {
#pragma unroll
    for (int k = 0; k < K; ++k) v[k] = lds[0][k] + lds[1][k] + lds[2][k] + lds[3][k];
  }
}

// ---------------- fp16 helpers ----------------
__device__ inline uint_t pack2h(float lo, float hi) {     // RNE
  return (uint_t)__half_as_ushort(__float2half(lo)) |
         ((uint_t)__half_as_ushort(__float2half(hi)) << 16);
}
__device__ inline float h_lo(uint_t w) {
  return __half2float(__ushort_as_half((unsigned short)(w & 0xFFFFu)));
}
__device__ inline float h_hi(uint_t w) {
  return __half2float(__ushort_as_half((unsigned short)(w >> 16)));
}

// load 8 consecutive positions for all 3 channels
template <bool H16>
__device__ inline void load3x8(const float* __restrict__ X,
                               const ushort_t* __restrict__ XH,
                               size_t e, float (&f)[3][8]) {
#pragma unroll
  for (int c = 0; c < 3; ++c) {
    const size_t a = e + (size_t)c * POS;
    if constexpr (H16) {
      const uint4 v = *(const uint4*)(XH + a);
      f[c][0] = h_lo(v.x); f[c][1] = h_hi(v.x);
      f[c][2] = h_lo(v.y); f[c][3] = h_hi(v.y);
      f[c][4] = h_lo(v.z); f[c][5] = h_hi(v.z);
      f[c][6] = h_lo(v.w); f[c][7] = h_hi(v.w);
    } else {
      const float4 u0 = *(const float4*)(X + a);
      const float4 u1 = *(const float4*)(X + a + 4);
      f[c][0] = u0.x; f[c][1] = u0.y; f[c][2] = u0.z; f[c][3] = u0.w;
      f[c][4] = u1.x; f[c][5] = u1.y; f[c][6] = u1.z; f[c][7] = u1.w;
    }
  }
}

__device__ inline void store8h(ushort_t* __restrict__ XH, size_t e,
                               const float (&g)[8]) {
  uint4 h;
  h.x = pack2h(g[0], g[1]);
  h.y = pack2h(g[2], g[3]);
  h.z = pack2h(g[4], g[5]);
  h.w = pack2h(g[6], g[7]);
  *(uint4*)(XH + e) = h;
}

// ---------------- raw moments -> mean/cov ----------------
__device__ inline void moments_to_mc(const double (&v)[9], double (&m)[3],
                                     double (&C)[3][3]) {
  const double M = (double)MLL;
  m[0] = v[0] / M; m[1] = v[1] / M; m[2] = v[2] / M;
  C[0][0] = v[3] / M - m[0] * m[0];
  C[1][1] = v[4] / M - m[1] * m[1];
  C[2][2] = v[5] / M - m[2] * m[2];
  C[0][1] = C[1][0] = v[6] / M - m[0] * m[1];
  C[0][2] = C[2][0] = v[7] / M - m[0] * m[2];
  C[1][2] = C[2][1] = v[8] / M - m[1] * m[2];
}

// ---- reduce slice s's 128x9 partial moments; result valid on thread 0 ----
__device__ inline void slice_reduce9(const double* __restrict__ P, int s,
                                     double (&v)[9]) {
#pragma unroll
  for (int k = 0; k < 9; ++k) v[k] = 0.0;
  if (threadIdx.x < SBLK) {
    const double* p = P + ((size_t)s * SBLK + threadIdx.x) * 9;
#pragma unroll
    for (int k = 0; k < 9; ++k) v[k] = p[k];
  }
  block_reduce_to0<9>(v);
}

// ---- analytic BN of y = Wk*t + bk from raw moments of t; folded to 12 floats:
//      dst[o*3+c] = s_o*Wk[o][c]; dst[9+o] = s_o*bk[o] + (be_o - mean_y*s_o) ----
__device__ inline void fold_math(const double (&v)[9], const float* __restrict__ Wk,
                                 const float* __restrict__ bk,
                                 const float* __restrict__ gk,
                                 const float* __restrict__ bek, int n,
                                 float* __restrict__ dst) {
  double m[3], C[3][3];
  moments_to_mc(v, m, C);
  for (int o = 0; o < 3; ++o) {
    const double w0 = Wk[n * 9 + o * 3 + 0];
    const double w1 = Wk[n * 9 + o * 3 + 1];
    const double w2 = Wk[n * 9 + o * 3 + 2];
    const double my = w0 * m[0] + w1 * m[1] + w2 * m[2] + (double)bk[n * 3 + o];
    const double vy = w0 * w0 * C[0][0] + w1 * w1 * C[1][1] + w2 * w2 * C[2][2] +
                      2.0 * (w0 * w1 * C[0][1] + w0 * w2 * C[0][2] + w1 * w2 * C[1][2]);
    const double sc = (double)gk[n * 3 + o] / sqrt(vy + 1e-5);
    const double tt = (double)bek[n * 3 + o] - my * sc;
    dst[o * 3 + 0] = (float)(sc * w0);
    dst[o * 3 + 1] = (float)(sc * w1);
    dst[o * 3 + 2] = (float)(sc * w2);
    dst[9 + o]     = (float)(sc * (double)bk[n * 3 + o] + tt);
  }
}

// ---- bn3 + bn4 analytic from a2-moments; folded to 16 floats:
//      [0..8]=F3, [9..11]=c3, [12..14]=s4*W4, [15]=s4*b4+t4 ----
__device__ inline void fold34_math(const double (&v)[9], const float* __restrict__ W3,
                                   const float* __restrict__ b3,
                                   const float* __restrict__ g3,
                                   const float* __restrict__ be3,
                                   const float* __restrict__ W4,
                                   const float* __restrict__ b4,
                                   const float* __restrict__ g4,
                                   const float* __restrict__ be4, int n,
                                   float* __restrict__ dst) {
  double m[3], C[3][3];
  moments_to_mc(v, m, C);
  double F3d[3][3], c3d[3];
  for (int o = 0; o < 3; ++o) {
    const double w0 = W3[n * 9 + o * 3 + 0];
    const double w1 = W3[n * 9 + o * 3 + 1];
    const double w2 = W3[n * 9 + o * 3 + 2];
    const double m3 = w0 * m[0] + w1 * m[1] + w2 * m[2] + (double)b3[n * 3 + o];
    const double vy = w0 * w0 * C[0][0] + w1 * w1 * C[1][1] + w2 * w2 * C[2][2] +
                      2.0 * (w0 * w1 * C[0][1] + w0 * w2 * C[0][2] + w1 * w2 * C[1][2]);
    const double s3 = (double)g3[n * 3 + o] / sqrt(vy + 1e-5);
    const double t3 = (double)be3[n * 3 + o] - m3 * s3;
    F3d[o][0] = s3 * w0; F3d[o][1] = s3 * w1; F3d[o][2] = s3 * w2;
    c3d[o] = s3 * (double)b3[n * 3 + o] + t3;
    dst[o * 3 + 0] = (float)F3d[o][0];
    dst[o * 3 + 1] = (float)F3d[o][1];
    dst[o * 3 + 2] = (float)F3d[o][2];
    dst[9 + o]     = (float)c3d[o];
  }
  double q[3] = {0.0, 0.0, 0.0};
  double d = (double)b4[n];
  for (int o = 0; o < 3; ++o) {
    const double w4o = W4[n * 3 + o];
    q[0] += w4o * F3d[o][0];
    q[1] += w4o * F3d[o][1];
    q[2] += w4o * F3d[o][2];
    d += w4o * c3d[o];
  }
  const double m4 = q[0] * m[0] + q[1] * m[1] + q[2] * m[2] + d;
  double v4 = 0.0;
  for (int i = 0; i < 3; ++i)
    for (int j = 0; j < 3; ++j) v4 += q[i] * q[j] * C[i][j];
  const double s4 = (double)g4[n] / sqrt(v4 + 1e-5);
  const double t4 = (double)be4[n] - m4 * s4;
  for (int o = 0; o < 3; ++o) dst[12 + o] = (float)(s4 * (double)W4[n * 3 + o]);
  dst[15] = (float)(s4 * (double)b4[n] + t4);
}

// ---------------- pass 1: raw moments of x (+ fp16 store, zero loss) -------
template <bool STORE>
__global__ __launch_bounds__(256) void pass1_kernel(
    const float* __restrict__ x1, const float* __restrict__ x2,
    ushort_t* __restrict__ xh1, ushort_t* __restrict__ xh2,
    double* __restrict__ P0, double* __restrict__ lossAcc,
    uint_t* __restrict__ cnt) {
  if (blockIdx.x == 0 && blockIdx.y == 0 && threadIdx.x == 0) {
    *lossAcc = 0.0;
    *cnt = 0u;
  }
  const int u = blockIdx.y;        // 0..191
  const int s = u % 24;
  const int b = u / 24;
  const int n = s >> 1;
  const float* __restrict__ X = (s & 1) ? x2 : x1;
  ushort_t* __restrict__ XH = (s & 1) ? xh2 : xh1;
  const size_t off0 = (size_t)((b * NH + n) * 3) * POS + (size_t)blockIdx.x * CSPAN;

  float acc[9] = {0.f, 0.f, 0.f, 0.f, 0.f, 0.f, 0.f, 0.f, 0.f};
#pragma unroll 2
  for (int i = 0; i < 4; ++i) {
    const size_t e = off0 + i * 2048 + threadIdx.x * 8;
    float f[3][8];
    load3x8<false>(X, nullptr, e, f);
    if constexpr (STORE) {
#pragma unroll
      for (int c = 0; c < 3; ++c) store8h(XH, e + (size_t)c * POS, f[c]);
    }
#pragma unroll
    for (int j = 0; j < 8; ++j) {
      const float X0 = f[0][j], X1 = f[1][j], X2 = f[2][j];
      acc[0] += X0;      acc[1] += X1;      acc[2] += X2;
      acc[3] += X0 * X0; acc[4] += X1 * X1; acc[5] += X2 * X2;
      acc[6] += X0 * X1; acc[7] += X0 * X2; acc[8] += X1 * X2;
    }
  }
  double v9[9];
#pragma unroll
  for (int k = 0; k < 9; ++k) v9[k] = (double)acc[k];
  block_reduce_to0<9>(v9);
  if (threadIdx.x == 0) {
    double* dst = P0 + ((size_t)s * SBLK + b * 16 + blockIdx.x) * 9;
#pragma unroll
    for (int k = 0; k < 9; ++k) dst[k] = v9[k];
  }
}

// ---------------- pass 2: fold bn1; moments of a -------------------------
template <bool H16>
__global__ __launch_bounds__(256) void pass2_kernel(
    const float* __restrict__ x1, const float* __restrict__ x2,
    const ushort_t* __restrict__ xh1, const ushort_t* __restrict__ xh2,
    const float* __restrict__ W1, const float* __restrict__ b1,
    const float* __restrict__ g1, const float* __restrict__ be1,
    const double* __restrict__ P0, double* __restrict__ P1) {
  const int u = blockIdx.y;
  const int s = u % 24;
  const int b = u / 24;
  const int n = s >> 1;
  const float* __restrict__ X = (s & 1) ? x2 : x1;
  const ushort_t* __restrict__ XH = (s & 1) ? xh2 : xh1;
  const size_t off0 = (size_t)((b * NH + n) * 3) * POS + (size_t)blockIdx.x * CSPAN;

  __shared__ float sf1[12];
  {
    double v[9];
    slice_reduce9(P0, s, v);
    if (threadIdx.x == 0) fold_math(v, W1, b1, g1, be1, n, sf1);
    __syncthreads();
  }
  float w1f[3][3], c1v[3];
#pragma unroll
  for (int o = 0; o < 3; ++o) {
#pragma unroll
    for (int c = 0; c < 3; ++c) w1f[o][c] = sf1[o * 3 + c];
    c1v[o] = sf1[9 + o];
  }

  float acc[9] = {0.f, 0.f, 0.f, 0.f, 0.f, 0.f, 0.f, 0.f, 0.f};
#pragma unroll 2
  for (int i = 0; i < 4; ++i) {
    const size_t e = off0 + i * 2048 + threadIdx.x * 8;
    float f[3][8];
    load3x8<H16>(X, XH, e, f);
#pragma unroll
    for (int j = 0; j < 8; ++j) {
      const float X0 = f[0][j], X1 = f[1][j], X2 = f[2][j];
      const float A0 = fmaxf(0.f, fmaf(w1f[0][0], X0, fmaf(w1f[0][1], X1, fmaf(w1f[0][2], X2, c1v[0]))));
      const float A1 = fmaxf(0.f, fmaf(w1f[1][0], X0, fmaf(w1f[1][1], X1, fmaf(w1f[1][2], X2, c1v[1]))));
      const float A2v= fmaxf(0.f, fmaf(w1f[2][0], X0, fmaf(w1f[2][1], X1, fmaf(w1f[2][2], X2, c1v[2]))));
      acc[0] += A0;       acc[1] += A1;       acc[2] += A2v;
      acc[3] += A0 * A0;  acc[4] += A1 * A1;  acc[5] += A2v * A2v;
      acc[6] += A0 * A1;  acc[7] += A0 * A2v; acc[8] += A1 * A2v;
    }
  }
  double v9[9];
#pragma unroll
  for (int k = 0; k < 9; ++k) v9[k] = (double)acc[k];
  block_reduce_to0<9>(v9);
  if (threadIdx.x == 0) {
    double* dst = P1 + ((size_t)s * SBLK + b * 16 + blockIdx.x) * 9;
#pragma unroll
    for (int k = 0; k < 9; ++k) dst[k] = v9[k];
  }
}

// ---------------- pass 3: fold bn1,bn2; moments of a2 (read-only) ---------
template <bool H16>
__global__ __launch_bounds__(256) void pass3_kernel(
    const float* __restrict__ x1, const float* __restrict__ x2,
    const ushort_t* __restrict__ xh1, const ushort_t* __restrict__ xh2,
    const float* __restrict__ W1, const float* __restrict__ b1,
    const float* __restrict__ g1, const float* __restrict__ be1,
    const float* __restrict__ W2, const float* __restrict__ b2,
    const float* __restrict__ g2, const float* __restrict__ be2,
    const double* __restrict__ P0, const double* __restrict__ P1,
    double* __restrict__ P2) {
  const int u = blockIdx.y;
  const int s = u % 24;
  const int b = u / 24;
  const int n = s >> 1;
  const float* __restrict__ X = (s & 1) ? x2 : x1;
  const ushort_t* __restrict__ XH = (s & 1) ? xh2 : xh1;
  const size_t off0 = (size_t)((b * NH + n) * 3) * POS + (size_t)blockIdx.x * CSPAN;

  __shared__ float sf1[12], sf2[12];
  {
    double v[9];
    slice_reduce9(P0, s, v);
    if (threadIdx.x == 0) fold_math(v, W1, b1, g1, be1, n, sf1);
    slice_reduce9(P1, s, v);
    if (threadIdx.x == 0) fold_math(v, W2, b2, g2, be2, n, sf2);
    __syncthreads();
  }
  float w1f[3][3], c1v[3], w2f[3][3], c2v[3];
#pragma unroll
  for (int o = 0; o < 3; ++o) {
#pragma unroll
    for (int c = 0; c < 3; ++c) {
      w1f[o][c] = sf1[o * 3 + c];
      w2f[o][c] = sf2[o * 3 + c];
    }
    c1v[o] = sf1[9 + o];
    c2v[o] = sf2[9 + o];
  }

  float acc[9] = {0.f, 0.f, 0.f, 0.f, 0.f, 0.f, 0.f, 0.f, 0.f};
#pragma unroll 2
  for (int i = 0; i < 4; ++i) {
    const size_t e = off0 + i * 2048 + threadIdx.x * 8;
    float f[3][8];
    load3x8<H16>(X, XH, e, f);
#pragma unroll
    for (int j = 0; j < 8; ++j) {
      const float X0 = f[0][j], X1 = f[1][j], X2 = f[2][j];
      const float a0 = fmaxf(0.f, fmaf(w1f[0][0], X0, fmaf(w1f[0][1], X1, fmaf(w1f[0][2], X2, c1v[0]))));
      const float a1 = fmaxf(0.f, fmaf(w1f[1][0], X0, fmaf(w1f[1][1], X1, fmaf(w1f[1][2], X2, c1v[1]))));
      const float a2 = fmaxf(0.f, fmaf(w1f[2][0], X0, fmaf(w1f[2][1], X1, fmaf(w1f[2][2], X2, c1v[2]))));
      const float A0 = fmaxf(0.f, fmaf(w2f[0][0], a0, fmaf(w2f[0][1], a1, fmaf(w2f[0][2], a2, c2v[0]))));
      const float A1 = fmaxf(0.f, fmaf(w2f[1][0], a0, fmaf(w2f[1][1], a1, fmaf(w2f[1][2], a2, c2v[1]))));
      const float A2v= fmaxf(0.f, fmaf(w2f[2][0], a0, fmaf(w2f[2][1], a1, fmaf(w2f[2][2], a2, c2v[2]))));
      acc[0] += A0;       acc[1] += A1;       acc[2] += A2v;
      acc[3] += A0 * A0;  acc[4] += A1 * A1;  acc[5] += A2v * A2v;
      acc[6] += A0 * A1;  acc[7] += A0 * A2v; acc[8] += A1 * A2v;
    }
  }
  double v9[9];
#pragma unroll
  for (int k = 0; k < 9; ++k) v9[k] = (double)acc[k];
  block_reduce_to0<9>(v9);
  if (threadIdx.x == 0) {
    double* dst = P2 + ((size_t)s * SBLK + b * 16 + blockIdx.x) * 9;
#pragma unroll
    for (int k = 0; k < 9; ++k) dst[k] = v9[k];
  }
}

// ---------------- full chain x -> a -> a2 -> z -> p (S = 40 floats) -------
__device__ inline void full_chain(const float (&S)[40], const float (&w5)[3],
                                  const float (&b5v)[3], float v0, float v1,
                                  float v2, float (&z)[3], float (&p)[3]) {
  const float t0 = fmaxf(0.f, fmaf(S[0], v0, fmaf(S[1], v1, fmaf(S[2], v2, S[9]))));
  const float t1 = fmaxf(0.f, fmaf(S[3], v0, fmaf(S[4], v1, fmaf(S[5], v2, S[10]))));
  const float t2 = fmaxf(0.f, fmaf(S[6], v0, fmaf(S[7], v1, fmaf(S[8], v2, S[11]))));
  const float a0 = fmaxf(0.f, fmaf(S[12], t0, fmaf(S[13], t1, fmaf(S[14], t2, S[21]))));
  const float a1 = fmaxf(0.f, fmaf(S[15], t0, fmaf(S[16], t1, fmaf(S[17], t2, S[22]))));
  const float a2 = fmaxf(0.f, fmaf(S[18], t0, fmaf(S[19], t1, fmaf(S[20], t2, S[23]))));
  z[0] = fmaf(S[24], a0, fmaf(S[25], a1, fmaf(S[26], a2, S[33])));
  z[1] = fmaf(S[27], a0, fmaf(S[28], a1, fmaf(S[29], a2, S[34])));
  z[2] = fmaf(S[30], a0, fmaf(S[31], a1, fmaf(S[32], a2, S[35])));
  const float y4 = fmaf(S[36], z[0], fmaf(S[37], z[1], fmaf(S[38], z[2], S[39])));
  const float h = fmaxf(0.f, y4);
#pragma unroll
  for (int o = 0; o < 3; ++o) p[o] = fmaf(w5[o], h, b5v[o]);
}

// ---------------- pass 4: folds; cosine loss; atomic finalize -------------
template <bool H16>
__global__ __launch_bounds__(256) void pass4_kernel(
    const float* __restrict__ x1, const float* __restrict__ x2,
    const ushort_t* __restrict__ xh1, const ushort_t* __restrict__ xh2,
    const float* __restrict__ W1, const float* __restrict__ b1,
    const float* __restrict__ g1, const float* __restrict__ be1,
    const float* __restrict__ W2, const float* __restrict__ b2,
    const float* __restrict__ g2, const float* __restrict__ be2,
    const float* __restrict__ W3, const float* __restrict__ b3,
    const float* __restrict__ g3, const float* __restrict__ be3,
    const float* __restrict__ W4, const float* __restrict__ b4,
    const float* __restrict__ g4, const float* __restrict__ be4,
    const float* __restrict__ W5, const float* __restrict__ b5,
    const double* __restrict__ P0, const double* __restrict__ P1,
    const double* __restrict__ P2, double* __restrict__ lossAcc,
    uint_t* __restrict__ cnt, float* __restrict__ out) {
  const int u = blockIdx.y;        // 0..95
  const int n = u % 12;
  const int b = u / 12;
  const size_t off0 = (size_t)((b * NH + n) * 3) * POS + (size_t)blockIdx.x * CSPAN;

  __shared__ float sh[2][40];
  {
    double v[9];
#pragma unroll
    for (int br = 0; br < 2; ++br) {
      const int s = 2 * n + br;
      slice_reduce9(P0, s, v);
      if (threadIdx.x == 0) fold_math(v, W1, b1, g1, be1, n, &sh[br][0]);
      slice_reduce9(P1, s, v);
      if (threadIdx.x == 0) fold_math(v, W2, b2, g2, be2, n, &sh[br][12]);
      slice_reduce9(P2, s, v);
      if (threadIdx.x == 0)
        fold34_math(v, W3, b3, g3, be3, W4, b4, g4, be4, n, &sh[br][24]);
    }
    __syncthreads();
  }
  float S0[40], S1[40];
#pragma unroll
  for (int k = 0; k < 40; ++k) {
    S0[k] = sh[0][k];
    S1[k] = sh[1][k];
  }
  float w5[3], b5v[3];
#pragma unroll
  for (int o = 0; o < 3; ++o) {
    w5[o]  = W5[n * 3 + o];
    b5v[o] = b5[n * 3 + o];
  }

  float acc = 0.f;
  for (int i = 0; i < 4; ++i) {
    const size_t e = off0 + i * 2048 + threadIdx.x * 8;
    float fA[3][8], fB[3][8];
    load3x8<H16>(x1, xh1, e, fA);
    load3x8<H16>(x2, xh2, e, fB);
#pragma unroll
    for (int j = 0; j < 8; ++j) {
      float z1[3], p1[3], z2[3], p2[3];
      full_chain(S0, w5, b5v, fA[0][j], fA[1][j], fA[2][j], z1, p1);
      full_chain(S1, w5, b5v, fB[0][j], fB[1][j], fB[2][j], z2, p2);

      const float d12 = p1[0] * z2[0] + p1[1] * z2[1] + p1[2] * z2[2];
      const float pp1 = p1[0] * p1[0] + p1[1] * p1[1] + p1[2] * p1[2];
      const float zz2 = z2[0] * z2[0] + z2[1] * z2[1] + z2[2] * z2[2];
      acc += d12 * __builtin_amdgcn_rsqf(fmaxf(pp1, 1e-16f)) *
                   __builtin_amdgcn_rsqf(fmaxf(zz2, 1e-16f));

      const float d21 = p2[0] * z1[0] + p2[1] * z1[1] + p2[2] * z1[2];
      const float pp2 = p2[0] * p2[0] + p2[1] * p2[1] + p2[2] * p2[2];
      const float zz1 = z1[0] * z1[0] + z1[1] * z1[1] + z1[2] * z1[2];
      acc += d21 * __builtin_amdgcn_rsqf(fmaxf(pp2, 1e-16f)) *
                   __builtin_amdgcn_rsqf(fmaxf(zz1, 1e-16f));
    }
  }

  double v[1] = {(double)acc};
  block_reduce_to0<1>(v);
  if (threadIdx.x == 0) {
    atomicAdd(lossAcc, v[0]);
    __threadfence();
    const uint_t total = gridDim.x * gridDim.y;
    const uint_t old = atomicAdd(cnt, 1u);
    if (old == total - 1u) {
      __threadfence();
      const double tot = atomicAdd(lossAcc, 0.0);  // coherent read-back
      out[0] = (float)(-0.5 * tot / (double)MLL);
    }
  }
}

// ---------------- launch ----------------
extern "C" void kernel_launch(void* const* d_in, const int* in_sizes, int n_in,
                              void* d_out, int out_size, void* d_ws, size_t ws_size,
                              hipStream_t stream) {
  const float* x1  = (const float*)d_in[0];
  const float* x2  = (const float*)d_in[1];
  const float* W1  = (const float*)d_in[2];
  const float* b1  = (const float*)d_in[3];
  const float* g1  = (const float*)d_in[4];
  const float* be1 = (const float*)d_in[5];
  const float* W2  = (const float*)d_in[6];
  const float* b2  = (const float*)d_in[7];
  const float* g2  = (const float*)d_in[8];
  const float* be2 = (const float*)d_in[9];
  const float* W3  = (const float*)d_in[10];
  const float* b3  = (const float*)d_in[11];
  const float* g3  = (const float*)d_in[12];
  const float* be3 = (const float*)d_in[13];
  const float* W4  = (const float*)d_in[14];
  const float* b4  = (const float*)d_in[15];
  const float* g4  = (const float*)d_in[16];
  const float* be4 = (const float*)d_in[17];
  const float* W5  = (const float*)d_in[18];
  const float* b5  = (const float*)d_in[19];

  const bool big = ws_size >= NEED_BYTES;
  ushort_t* xh1 = nullptr;
  ushort_t* xh2 = nullptr;
  double* dbase;
  if (big) {
    xh1 = (ushort_t*)d_ws;
    xh2 = xh1 + NTOT;
    dbase = (double*)(xh2 + NTOT);
  } else {
    dbase = (double*)d_ws;
  }
  double* P0 = dbase;
  double* P1 = P0 + P_CNT;
  double* P2 = P1 + P_CNT;
  double* lossAcc = P2 + P_CNT;
  uint_t* cnt = (uint_t*)(lossAcc + 1);

  const dim3 blk(256);
  const dim3 gA(16, 192);
  const dim3 gD(16, 96);

  if (big) {
    pass1_kernel<true><<<gA, blk, 0, stream>>>(x1, x2, xh1, xh2, P0, lossAcc, cnt);
    pass2_kernel<true><<<gA, blk, 0, stream>>>(x1, x2, xh1, xh2, W1, b1, g1, be1,
                                               P0, P1);
    pass3_kernel<true><<<gA, blk, 0, stream>>>(x1, x2, xh1, xh2, W1, b1, g1, be1,
                                               W2, b2, g2, be2, P0, P1, P2);
    pass4_kernel<true><<<gD, blk, 0, stream>>>(x1, x2, xh1, xh2, W1, b1, g1, be1,
                                               W2, b2, g2, be2, W3, b3, g3, be3,
                                               W4, b4, g4, be4, W5, b5, P0, P1,
                                               P2, lossAcc, cnt, (float*)d_out);
  } else {
    pass1_kernel<false><<<gA, blk, 0, stream>>>(x1, x2, nullptr, nullptr, P0,
                                                lossAcc, cnt);
    pass2_kernel<false><<<gA, blk, 0, stream>>>(x1, x2, nullptr, nullptr, W1, b1,
                                                g1, be1, P0, P1);
    pass3_kernel<false><<<gA, blk, 0, stream>>>(x1, x2, nullptr, nullptr, W1, b1,
                                                g1, be1, W2, b2, g2, be2, P0, P1,
                                                P2);
    pass4_kernel<false><<<gD, blk, 0, stream>>>(x1, x2, nullptr, nullptr, W1, b1,
                                                g1, be1, W2, b2, g2, be2, W3, b3,
                                                g3, be3, W4, b4, g4, be4, W5, b5,
                                                P0, P1, P2, lossAcc, cnt,
                                                (float*)d_out);
  }
}

// Round 5
// 499.089 us; speedup vs baseline: 1.1630x; 1.1630x over previous
//
#include <hip/hip_runtime.h>
#include <hip/hip_fp16.h>
#include <math.h>

// ---------------------------------------------------------------------------
// SimSiam head loss, 12 heads, fp32 in, B=8 H=512 W=768 -> per head (8,3,512,256)
//
// R7 = R6 structure with __builtin_nontemporal_load removed (suspected cause
// of the R6 container failure; only new compiler surface vs the passing R5).
//   - R4 lesson: no cooperative/grid.sync (graph capture deadlocks it).
//   - R5 lesson: BN folds in tiny 24-block stats kernels (in-pass double-math
//     preambles crushed occupancy: VGPR 120, occ 19.6%, 153 us pass4).
//   - All fp16 passes are latency-bound -> 2-deep explicit load prefetch,
//     inline fp16 unpack (low VGPR).
// Pipeline (7 dispatches):
//   pass1: read fp32 x -> x 9-moments -> P0; write fp16(x); zero loss/cnt
//   stats1: fold bn1 -> derived[s*40+0..11]
//   pass2: read fp16 x, a = relu(W1f x+c1), 9-moments(a) -> P1
//   stats2: fold bn2 -> derived[s*40+12..23]
//   pass3: read fp16 x, a -> a2, 9-moments(a2) -> P2        (read-only)
//   stats3: fold bn3+bn4 -> derived[s*40+24..39]
//   pass4: read fp16 x both latents, full chain x->a->a2->z->p, cosine loss,
//          atomicAdd + last-block finalize (pattern proven in R5, absmax 0.0).
// Fallback (small ws): same kernels re-reading fp32 x (H16=false).
// ---------------------------------------------------------------------------

typedef unsigned short ushort_t;
typedef unsigned int   uint_t;

constexpr int   NH      = 12;
constexpr int   POS     = 131072;               // floats per channel per (b,head)
constexpr int   NB      = 8;
constexpr long long MLL = (long long)NB * POS;  // 1,048,576 positions per slice
constexpr int   CSPAN   = POS / 16;             // 8192 floats/channel per block
constexpr int   SBLK    = 128;                  // blocks per slice = 8 b * 16 x
constexpr int   NTOT    = NB * NH * 3 * POS;    // 37,748,736 elements per latent

constexpr size_t P_CNT      = (size_t)24 * SBLK * 9;   // doubles per P array
constexpr size_t NEED_BYTES = (size_t)NTOT * 2 * 2 + 3 * P_CNT * 8 + 32 +
                              (size_t)24 * 40 * 4;

// ---------------- block reduction: 256 threads -> thread 0 ----------------
template <int K>
__device__ inline void block_reduce_to0(double (&v)[K]) {
#pragma unroll
  for (int off = 32; off > 0; off >>= 1) {
#pragma unroll
    for (int k = 0; k < K; ++k) v[k] += __shfl_down(v[k], off, 64);
  }
  __shared__ double lds[4][K];
  __syncthreads();
  const int lane = threadIdx.x & 63;
  const int wv   = threadIdx.x >> 6;
  if (lane == 0) {
#pragma unroll
    for (int k = 0; k < K; ++k) lds[wv][k] = v[k];
  }
  __syncthreads();
  if (threadIdx.x == 0) {
#pragma unroll
    for (int k = 0; k < K; ++k) v[k] = lds[0][k] + lds[1][k] + lds[2][k] + lds[3][k];
  }
}

// ---------------- fp16 helpers ----------------
__device__ inline uint_t pack2h(float lo, float hi) {     // RNE
  return (uint_t)__half_as_ushort(__float2half(lo)) |
         ((uint_t)__half_as_ushort(__float2half(hi)) << 16);
}

// element j (0..7) of a uint4 of 8 packed halves; j compile-time after unroll
__device__ inline float hget(const uint4& v, int j) {
  const uint_t w = (&v.x)[j >> 1];
  return __half2float(__ushort_as_half(
      (j & 1) ? (unsigned short)(w >> 16) : (unsigned short)(w & 0xFFFFu)));
}

__device__ inline void store8h(ushort_t* __restrict__ XH, size_t e,
                               const float (&g)[8]) {
  uint4 h;
  h.x = pack2h(g[0], g[1]);
  h.y = pack2h(g[2], g[3]);
  h.z = pack2h(g[4], g[5]);
  h.w = pack2h(g[6], g[7]);
  *(uint4*)(XH + e) = h;
}

// ---------------- raw moments -> mean/cov ----------------
__device__ inline void moments_to_mc(const double (&v)[9], double (&m)[3],
                                     double (&C)[3][3]) {
  const double M = (double)MLL;
  m[0] = v[0] / M; m[1] = v[1] / M; m[2] = v[2] / M;
  C[0][0] = v[3] / M - m[0] * m[0];
  C[1][1] = v[4] / M - m[1] * m[1];
  C[2][2] = v[5] / M - m[2] * m[2];
  C[0][1] = C[1][0] = v[6] / M - m[0] * m[1];
  C[0][2] = C[2][0] = v[7] / M - m[0] * m[2];
  C[1][2] = C[2][1] = v[8] / M - m[1] * m[2];
}

// ---- analytic BN of y = Wk*t + bk from raw moments of t; folded 12 floats ----
__device__ inline void fold_math(const double (&v)[9], const float* __restrict__ Wk,
                                 const float* __restrict__ bk,
                                 const float* __restrict__ gk,
                                 const float* __restrict__ bek, int n,
                                 float* __restrict__ dst) {
  double m[3], C[3][3];
  moments_to_mc(v, m, C);
  for (int o = 0; o < 3; ++o) {
    const double w0 = Wk[n * 9 + o * 3 + 0];
    const double w1 = Wk[n * 9 + o * 3 + 1];
    const double w2 = Wk[n * 9 + o * 3 + 2];
    const double my = w0 * m[0] + w1 * m[1] + w2 * m[2] + (double)bk[n * 3 + o];
    const double vy = w0 * w0 * C[0][0] + w1 * w1 * C[1][1] + w2 * w2 * C[2][2] +
                      2.0 * (w0 * w1 * C[0][1] + w0 * w2 * C[0][2] + w1 * w2 * C[1][2]);
    const double sc = (double)gk[n * 3 + o] / sqrt(vy + 1e-5);
    const double tt = (double)bek[n * 3 + o] - my * sc;
    dst[o * 3 + 0] = (float)(sc * w0);
    dst[o * 3 + 1] = (float)(sc * w1);
    dst[o * 3 + 2] = (float)(sc * w2);
    dst[9 + o]     = (float)(sc * (double)bk[n * 3 + o] + tt);
  }
}

// ---- bn3 + bn4 analytic from a2-moments; folded 16 floats ----
__device__ inline void fold34_math(const double (&v)[9], const float* __restrict__ W3,
                                   const float* __restrict__ b3,
                                   const float* __restrict__ g3,
                                   const float* __restrict__ be3,
                                   const float* __restrict__ W4,
                                   const float* __restrict__ b4,
                                   const float* __restrict__ g4,
                                   const float* __restrict__ be4, int n,
                                   float* __restrict__ dst) {
  double m[3], C[3][3];
  moments_to_mc(v, m, C);
  double F3d[3][3], c3d[3];
  for (int o = 0; o < 3; ++o) {
    const double w0 = W3[n * 9 + o * 3 + 0];
    const double w1 = W3[n * 9 + o * 3 + 1];
    const double w2 = W3[n * 9 + o * 3 + 2];
    const double m3 = w0 * m[0] + w1 * m[1] + w2 * m[2] + (double)b3[n * 3 + o];
    const double vy = w0 * w0 * C[0][0] + w1 * w1 * C[1][1] + w2 * w2 * C[2][2] +
                      2.0 * (w0 * w1 * C[0][1] + w0 * w2 * C[0][2] + w1 * w2 * C[1][2]);
    const double s3 = (double)g3[n * 3 + o] / sqrt(vy + 1e-5);
    const double t3 = (double)be3[n * 3 + o] - m3 * s3;
    F3d[o][0] = s3 * w0; F3d[o][1] = s3 * w1; F3d[o][2] = s3 * w2;
    c3d[o] = s3 * (double)b3[n * 3 + o] + t3;
    dst[o * 3 + 0] = (float)F3d[o][0];
    dst[o * 3 + 1] = (float)F3d[o][1];
    dst[o * 3 + 2] = (float)F3d[o][2];
    dst[9 + o]     = (float)c3d[o];
  }
  double q[3] = {0.0, 0.0, 0.0};
  double d = (double)b4[n];
  for (int o = 0; o < 3; ++o) {
    const double w4o = W4[n * 3 + o];
    q[0] += w4o * F3d[o][0];
    q[1] += w4o * F3d[o][1];
    q[2] += w4o * F3d[o][2];
    d += w4o * c3d[o];
  }
  const double m4 = q[0] * m[0] + q[1] * m[1] + q[2] * m[2] + d;
  double v4 = 0.0;
  for (int i = 0; i < 3; ++i)
    for (int j = 0; j < 3; ++j) v4 += q[i] * q[j] * C[i][j];
  const double s4 = (double)g4[n] / sqrt(v4 + 1e-5);
  const double t4 = (double)be4[n] - m4 * s4;
  for (int o = 0; o < 3; ++o) dst[12 + o] = (float)(s4 * (double)W4[n * 3 + o]);
  dst[15] = (float)(s4 * (double)b4[n] + t4);
}

// ---------------- moment accumulation ----------------
__device__ inline void acc9(float X0, float X1, float X2, float (&a)[9]) {
  a[0] += X0;      a[1] += X1;      a[2] += X2;
  a[3] += X0 * X0; a[4] += X1 * X1; a[5] += X2 * X2;
  a[6] += X0 * X1; a[7] += X0 * X2; a[8] += X1 * X2;
}

// fp32 fallback loader
__device__ inline void load3x8_f32(const float* __restrict__ X, size_t e,
                                   float (&f)[3][8]) {
#pragma unroll
  for (int c = 0; c < 3; ++c) {
    const size_t a = e + (size_t)c * POS;
    const float4 u0 = *(const float4*)(X + a);
    const float4 u1 = *(const float4*)(X + a + 4);
    f[c][0] = u0.x; f[c][1] = u0.y; f[c][2] = u0.z; f[c][3] = u0.w;
    f[c][4] = u1.x; f[c][5] = u1.y; f[c][6] = u1.z; f[c][7] = u1.w;
  }
}

// ---------------- pass 1: x moments (+ fp16 store, zero loss) -------------
template <bool STORE>
__global__ __launch_bounds__(256) void pass1_kernel(
    const float* __restrict__ x1, const float* __restrict__ x2,
    ushort_t* __restrict__ xh1, ushort_t* __restrict__ xh2,
    double* __restrict__ P0, double* __restrict__ lossAcc,
    uint_t* __restrict__ cnt) {
  if (blockIdx.x == 0 && blockIdx.y == 0 && threadIdx.x == 0) {
    *lossAcc = 0.0;
    *cnt = 0u;
  }
  const int u = blockIdx.y;        // 0..191
  const int s = u % 24;
  const int b = u / 24;
  const int n = s >> 1;
  const float* __restrict__ X = (s & 1) ? x2 : x1;
  ushort_t* __restrict__ XH = (s & 1) ? xh2 : xh1;
  const int tid = threadIdx.x;
  const size_t off0 = (size_t)((b * NH + n) * 3) * POS + (size_t)blockIdx.x * CSPAN;

  float acc[9] = {0.f, 0.f, 0.f, 0.f, 0.f, 0.f, 0.f, 0.f, 0.f};

  // software-pipelined: prefetch next iteration's 6 float4
  float4 cur[6];
#pragma unroll
  for (int c = 0; c < 3; ++c) {
    const size_t a = off0 + (size_t)c * POS + tid * 8;
    cur[2 * c]     = *(const float4*)(X + a);
    cur[2 * c + 1] = *(const float4*)(X + a + 4);
  }
#pragma unroll
  for (int i = 0; i < 4; ++i) {
    float4 nxt[6];
    if (i < 3) {
#pragma unroll
      for (int c = 0; c < 3; ++c) {
        const size_t a = off0 + (size_t)c * POS + (i + 1) * 2048 + tid * 8;
        nxt[2 * c]     = *(const float4*)(X + a);
        nxt[2 * c + 1] = *(const float4*)(X + a + 4);
      }
    }
    const size_t e = off0 + i * 2048 + tid * 8;
    float f[3][8];
#pragma unroll
    for (int c = 0; c < 3; ++c) {
      f[c][0] = cur[2 * c].x;     f[c][1] = cur[2 * c].y;
      f[c][2] = cur[2 * c].z;     f[c][3] = cur[2 * c].w;
      f[c][4] = cur[2 * c + 1].x; f[c][5] = cur[2 * c + 1].y;
      f[c][6] = cur[2 * c + 1].z; f[c][7] = cur[2 * c + 1].w;
    }
    if constexpr (STORE) {
#pragma unroll
      for (int c = 0; c < 3; ++c) store8h(XH, e + (size_t)c * POS, f[c]);
    }
#pragma unroll
    for (int j = 0; j < 8; ++j) acc9(f[0][j], f[1][j], f[2][j], acc);
    if (i < 3) {
#pragma unroll
      for (int k = 0; k < 6; ++k) cur[k] = nxt[k];
    }
  }

  double v9[9];
#pragma unroll
  for (int k = 0; k < 9; ++k) v9[k] = (double)acc[k];
  block_reduce_to0<9>(v9);
  if (threadIdx.x == 0) {
    double* dst = P0 + ((size_t)s * SBLK + b * 16 + blockIdx.x) * 9;
#pragma unroll
    for (int k = 0; k < 9; ++k) dst[k] = v9[k];
  }
}

// ---------------- stats kernels (24 blocks) ----------------
__global__ __launch_bounds__(256) void stats_fold_kernel(
    const double* __restrict__ P, const float* __restrict__ Wk,
    const float* __restrict__ bk, const float* __restrict__ gk,
    const float* __restrict__ bek, float* __restrict__ derived, int outoff) {
  const int s = blockIdx.x;
  double v[9] = {0, 0, 0, 0, 0, 0, 0, 0, 0};
  if (threadIdx.x < SBLK) {
    const double* p = P + ((size_t)s * SBLK + threadIdx.x) * 9;
#pragma unroll
    for (int k = 0; k < 9; ++k) v[k] = p[k];
  }
  block_reduce_to0<9>(v);
  if (threadIdx.x == 0)
    fold_math(v, Wk, bk, gk, bek, s >> 1, derived + s * 40 + outoff);
}

__global__ __launch_bounds__(256) void stats34_kernel(
    const double* __restrict__ P2, const float* __restrict__ W3,
    const float* __restrict__ b3, const float* __restrict__ g3,
    const float* __restrict__ be3, const float* __restrict__ W4,
    const float* __restrict__ b4, const float* __restrict__ g4,
    const float* __restrict__ be4, float* __restrict__ derived) {
  const int s = blockIdx.x;
  double v[9] = {0, 0, 0, 0, 0, 0, 0, 0, 0};
  if (threadIdx.x < SBLK) {
    const double* p = P2 + ((size_t)s * SBLK + threadIdx.x) * 9;
#pragma unroll
    for (int k = 0; k < 9; ++k) v[k] = p[k];
  }
  block_reduce_to0<9>(v);
  if (threadIdx.x == 0)
    fold34_math(v, W3, b3, g3, be3, W4, b4, g4, be4, s >> 1,
                derived + s * 40 + 24);
}

// ---------------- pass 2: moments of a = relu(W1f x + c1) -----------------
template <bool H16>
__global__ __launch_bounds__(256) void pass2_kernel(
    const float* __restrict__ x1, const float* __restrict__ x2,
    const ushort_t* __restrict__ xh1, const ushort_t* __restrict__ xh2,
    const float* __restrict__ derived, double* __restrict__ P1) {
  const int u = blockIdx.y;
  const int s = u % 24;
  const int b = u / 24;
  const int n = s >> 1;
  const float* __restrict__ X = (s & 1) ? x2 : x1;
  const ushort_t* __restrict__ XH = (s & 1) ? xh2 : xh1;
  const int tid = threadIdx.x;
  const size_t off0 = (size_t)((b * NH + n) * 3) * POS + (size_t)blockIdx.x * CSPAN;

  const float* D = derived + s * 40;   // uniform -> scalar loads
  float w1f[3][3], c1v[3];
#pragma unroll
  for (int o = 0; o < 3; ++o) {
#pragma unroll
    for (int c = 0; c < 3; ++c) w1f[o][c] = D[o * 3 + c];
    c1v[o] = D[9 + o];
  }

  float acc[9] = {0.f, 0.f, 0.f, 0.f, 0.f, 0.f, 0.f, 0.f, 0.f};

  if constexpr (H16) {
    uint4 cur[3];
#pragma unroll
    for (int c = 0; c < 3; ++c)
      cur[c] = *(const uint4*)(XH + off0 + (size_t)c * POS + tid * 8);
#pragma unroll
    for (int i = 0; i < 4; ++i) {
      uint4 nxt[3];
      if (i < 3) {
#pragma unroll
        for (int c = 0; c < 3; ++c)
          nxt[c] = *(const uint4*)(XH + off0 + (size_t)c * POS + (i + 1) * 2048 +
                                   tid * 8);
      }
#pragma unroll
      for (int j = 0; j < 8; ++j) {
        const float X0 = hget(cur[0], j), X1 = hget(cur[1], j), X2 = hget(cur[2], j);
        const float A0 = fmaxf(0.f, fmaf(w1f[0][0], X0, fmaf(w1f[0][1], X1, fmaf(w1f[0][2], X2, c1v[0]))));
        const float A1 = fmaxf(0.f, fmaf(w1f[1][0], X0, fmaf(w1f[1][1], X1, fmaf(w1f[1][2], X2, c1v[1]))));
        const float A2 = fmaxf(0.f, fmaf(w1f[2][0], X0, fmaf(w1f[2][1], X1, fmaf(w1f[2][2], X2, c1v[2]))));
        acc9(A0, A1, A2, acc);
      }
      if (i < 3) {
#pragma unroll
        for (int c = 0; c < 3; ++c) cur[c] = nxt[c];
      }
    }
  } else {
    for (int i = 0; i < 4; ++i) {
      const size_t e = off0 + i * 2048 + tid * 8;
      float f[3][8];
      load3x8_f32(X, e, f);
#pragma unroll
      for (int j = 0; j < 8; ++j) {
        const float X0 = f[0][j], X1 = f[1][j], X2 = f[2][j];
        const float A0 = fmaxf(0.f, fmaf(w1f[0][0], X0, fmaf(w1f[0][1], X1, fmaf(w1f[0][2], X2, c1v[0]))));
        const float A1 = fmaxf(0.f, fmaf(w1f[1][0], X0, fmaf(w1f[1][1], X1, fmaf(w1f[1][2], X2, c1v[1]))));
        const float A2 = fmaxf(0.f, fmaf(w1f[2][0], X0, fmaf(w1f[2][1], X1, fmaf(w1f[2][2], X2, c1v[2]))));
        acc9(A0, A1, A2, acc);
      }
    }
  }

  double v9[9];
#pragma unroll
  for (int k = 0; k < 9; ++k) v9[k] = (double)acc[k];
  block_reduce_to0<9>(v9);
  if (threadIdx.x == 0) {
    double* dst = P1 + ((size_t)s * SBLK + b * 16 + blockIdx.x) * 9;
#pragma unroll
    for (int k = 0; k < 9; ++k) dst[k] = v9[k];
  }
}

// ---------------- pass 3: moments of a2 (read-only) -----------------------
template <bool H16>
__global__ __launch_bounds__(256) void pass3_kernel(
    const float* __restrict__ x1, const float* __restrict__ x2,
    const ushort_t* __restrict__ xh1, const ushort_t* __restrict__ xh2,
    const float* __restrict__ derived, double* __restrict__ P2) {
  const int u = blockIdx.y;
  const int s = u % 24;
  const int b = u / 24;
  const int n = s >> 1;
  const float* __restrict__ X = (s & 1) ? x2 : x1;
  const ushort_t* __restrict__ XH = (s & 1) ? xh2 : xh1;
  const int tid = threadIdx.x;
  const size_t off0 = (size_t)((b * NH + n) * 3) * POS + (size_t)blockIdx.x * CSPAN;

  const float* D = derived + s * 40;
  float w1f[3][3], c1v[3], w2f[3][3], c2v[3];
#pragma unroll
  for (int o = 0; o < 3; ++o) {
#pragma unroll
    for (int c = 0; c < 3; ++c) {
      w1f[o][c] = D[o * 3 + c];
      w2f[o][c] = D[12 + o * 3 + c];
    }
    c1v[o] = D[9 + o];
    c2v[o] = D[21 + o];
  }

  float acc[9] = {0.f, 0.f, 0.f, 0.f, 0.f, 0.f, 0.f, 0.f, 0.f};

  auto body = [&](float X0, float X1, float X2) {
    const float a0 = fmaxf(0.f, fmaf(w1f[0][0], X0, fmaf(w1f[0][1], X1, fmaf(w1f[0][2], X2, c1v[0]))));
    const float a1 = fmaxf(0.f, fmaf(w1f[1][0], X0, fmaf(w1f[1][1], X1, fmaf(w1f[1][2], X2, c1v[1]))));
    const float a2 = fmaxf(0.f, fmaf(w1f[2][0], X0, fmaf(w1f[2][1], X1, fmaf(w1f[2][2], X2, c1v[2]))));
    const float A0 = fmaxf(0.f, fmaf(w2f[0][0], a0, fmaf(w2f[0][1], a1, fmaf(w2f[0][2], a2, c2v[0]))));
    const float A1 = fmaxf(0.f, fmaf(w2f[1][0], a0, fmaf(w2f[1][1], a1, fmaf(w2f[1][2], a2, c2v[1]))));
    const float A2 = fmaxf(0.f, fmaf(w2f[2][0], a0, fmaf(w2f[2][1], a1, fmaf(w2f[2][2], a2, c2v[2]))));
    acc9(A0, A1, A2, acc);
  };

  if constexpr (H16) {
    uint4 cur[3];
#pragma unroll
    for (int c = 0; c < 3; ++c)
      cur[c] = *(const uint4*)(XH + off0 + (size_t)c * POS + tid * 8);
#pragma unroll
    for (int i = 0; i < 4; ++i) {
      uint4 nxt[3];
      if (i < 3) {
#pragma unroll
        for (int c = 0; c < 3; ++c)
          nxt[c] = *(const uint4*)(XH + off0 + (size_t)c * POS + (i + 1) * 2048 +
                                   tid * 8);
      }
#pragma unroll
      for (int j = 0; j < 8; ++j)
        body(hget(cur[0], j), hget(cur[1], j), hget(cur[2], j));
      if (i < 3) {
#pragma unroll
        for (int c = 0; c < 3; ++c) cur[c] = nxt[c];
      }
    }
  } else {
    for (int i = 0; i < 4; ++i) {
      const size_t e = off0 + i * 2048 + tid * 8;
      float f[3][8];
      load3x8_f32(X, e, f);
#pragma unroll
      for (int j = 0; j < 8; ++j) body(f[0][j], f[1][j], f[2][j]);
    }
  }

  double v9[9];
#pragma unroll
  for (int k = 0; k < 9; ++k) v9[k] = (double)acc[k];
  block_reduce_to0<9>(v9);
  if (threadIdx.x == 0) {
    double* dst = P2 + ((size_t)s * SBLK + b * 16 + blockIdx.x) * 9;
#pragma unroll
    for (int k = 0; k < 9; ++k) dst[k] = v9[k];
  }
}

// ---------------- full chain x -> a -> a2 -> z -> p (S = 40 floats) -------
__device__ inline void full_chain(const float (&S)[40], const float (&w5)[3],
                                  const float (&b5v)[3], float v0, float v1,
                                  float v2, float (&z)[3], float (&p)[3]) {
  const float t0 = fmaxf(0.f, fmaf(S[0], v0, fmaf(S[1], v1, fmaf(S[2], v2, S[9]))));
  const float t1 = fmaxf(0.f, fmaf(S[3], v0, fmaf(S[4], v1, fmaf(S[5], v2, S[10]))));
  const float t2 = fmaxf(0.f, fmaf(S[6], v0, fmaf(S[7], v1, fmaf(S[8], v2, S[11]))));
  const float a0 = fmaxf(0.f, fmaf(S[12], t0, fmaf(S[13], t1, fmaf(S[14], t2, S[21]))));
  const float a1 = fmaxf(0.f, fmaf(S[15], t0, fmaf(S[16], t1, fmaf(S[17], t2, S[22]))));
  const float a2 = fmaxf(0.f, fmaf(S[18], t0, fmaf(S[19], t1, fmaf(S[20], t2, S[23]))));
  z[0] = fmaf(S[24], a0, fmaf(S[25], a1, fmaf(S[26], a2, S[33])));
  z[1] = fmaf(S[27], a0, fmaf(S[28], a1, fmaf(S[29], a2, S[34])));
  z[2] = fmaf(S[30], a0, fmaf(S[31], a1, fmaf(S[32], a2, S[35])));
  const float y4 = fmaf(S[36], z[0], fmaf(S[37], z[1], fmaf(S[38], z[2], S[39])));
  const float h = fmaxf(0.f, y4);
#pragma unroll
  for (int o = 0; o < 3; ++o) p[o] = fmaf(w5[o], h, b5v[o]);
}

// ---------------- pass 4: cosine loss + atomic finalize -------------------
template <bool H16>
__global__ __launch_bounds__(256) void pass4_kernel(
    const float* __restrict__ x1, const float* __restrict__ x2,
    const ushort_t* __restrict__ xh1, const ushort_t* __restrict__ xh2,
    const float* __restrict__ W5, const float* __restrict__ b5,
    const float* __restrict__ derived, double* __restrict__ lossAcc,
    uint_t* __restrict__ cnt, float* __restrict__ out) {
  const int u = blockIdx.y;        // 0..95
  const int n = u % 12;
  const int b = u / 12;
  const int tid = threadIdx.x;
  const size_t off0 = (size_t)((b * NH + n) * 3) * POS + (size_t)blockIdx.x * CSPAN;

  float S0[40], S1[40];
  {
    const float* D0 = derived + (size_t)(2 * n + 0) * 40;   // uniform
    const float* D1 = derived + (size_t)(2 * n + 1) * 40;
#pragma unroll
    for (int k = 0; k < 40; ++k) {
      S0[k] = D0[k];
      S1[k] = D1[k];
    }
  }
  float w5[3], b5v[3];
#pragma unroll
  for (int o = 0; o < 3; ++o) {
    w5[o]  = W5[n * 3 + o];
    b5v[o] = b5[n * 3 + o];
  }

  float acc = 0.f;

  auto body = [&](float xA0, float xA1, float xA2, float xB0, float xB1,
                  float xB2) {
    float z1[3], p1[3], z2[3], p2[3];
    full_chain(S0, w5, b5v, xA0, xA1, xA2, z1, p1);
    full_chain(S1, w5, b5v, xB0, xB1, xB2, z2, p2);
    const float d12 = p1[0] * z2[0] + p1[1] * z2[1] + p1[2] * z2[2];
    const float pp1 = p1[0] * p1[0] + p1[1] * p1[1] + p1[2] * p1[2];
    const float zz2 = z2[0] * z2[0] + z2[1] * z2[1] + z2[2] * z2[2];
    acc += d12 * __builtin_amdgcn_rsqf(fmaxf(pp1, 1e-16f)) *
                 __builtin_amdgcn_rsqf(fmaxf(zz2, 1e-16f));
    const float d21 = p2[0] * z1[0] + p2[1] * z1[1] + p2[2] * z1[2];
    const float pp2 = p2[0] * p2[0] + p2[1] * p2[1] + p2[2] * p2[2];
    const float zz1 = z1[0] * z1[0] + z1[1] * z1[1] + z1[2] * z1[2];
    acc += d21 * __builtin_amdgcn_rsqf(fmaxf(pp2, 1e-16f)) *
                 __builtin_amdgcn_rsqf(fmaxf(zz1, 1e-16f));
  };

  if constexpr (H16) {
    uint4 curA[3], curB[3];
#pragma unroll
    for (int c = 0; c < 3; ++c) {
      const size_t a = off0 + (size_t)c * POS + tid * 8;
      curA[c] = *(const uint4*)(xh1 + a);
      curB[c] = *(const uint4*)(xh2 + a);
    }
#pragma unroll
    for (int i = 0; i < 4; ++i) {
      uint4 nxtA[3], nxtB[3];
      if (i < 3) {
#pragma unroll
        for (int c = 0; c < 3; ++c) {
          const size_t a = off0 + (size_t)c * POS + (i + 1) * 2048 + tid * 8;
          nxtA[c] = *(const uint4*)(xh1 + a);
          nxtB[c] = *(const uint4*)(xh2 + a);
        }
      }
#pragma unroll
      for (int j = 0; j < 8; ++j)
        body(hget(curA[0], j), hget(curA[1], j), hget(curA[2], j),
             hget(curB[0], j), hget(curB[1], j), hget(curB[2], j));
      if (i < 3) {
#pragma unroll
        for (int c = 0; c < 3; ++c) {
          curA[c] = nxtA[c];
          curB[c] = nxtB[c];
        }
      }
    }
  } else {
    for (int i = 0; i < 4; ++i) {
      const size_t e = off0 + i * 2048 + tid * 8;
      float fA[3][8], fB[3][8];
      load3x8_f32(x1, e, fA);
      load3x8_f32(x2, e, fB);
#pragma unroll
      for (int j = 0; j < 8; ++j)
        body(fA[0][j], fA[1][j], fA[2][j], fB[0][j], fB[1][j], fB[2][j]);
    }
  }

  double v[1] = {(double)acc};
  block_reduce_to0<1>(v);
  if (threadIdx.x == 0) {
    atomicAdd(lossAcc, v[0]);
    __threadfence();
    const uint_t total = gridDim.x * gridDim.y;
    const uint_t old = atomicAdd(cnt, 1u);
    if (old == total - 1u) {
      __threadfence();
      const double tot = atomicAdd(lossAcc, 0.0);  // coherent read-back
      out[0] = (float)(-0.5 * tot / (double)MLL);
    }
  }
}

// ---------------- launch ----------------
extern "C" void kernel_launch(void* const* d_in, const int* in_sizes, int n_in,
                              void* d_out, int out_size, void* d_ws, size_t ws_size,
                              hipStream_t stream) {
  const float* x1  = (const float*)d_in[0];
  const float* x2  = (const float*)d_in[1];
  const float* W1  = (const float*)d_in[2];
  const float* b1  = (const float*)d_in[3];
  const float* g1  = (const float*)d_in[4];
  const float* be1 = (const float*)d_in[5];
  const float* W2  = (const float*)d_in[6];
  const float* b2  = (const float*)d_in[7];
  const float* g2  = (const float*)d_in[8];
  const float* be2 = (const float*)d_in[9];
  const float* W3  = (const float*)d_in[10];
  const float* b3  = (const float*)d_in[11];
  const float* g3  = (const float*)d_in[12];
  const float* be3 = (const float*)d_in[13];
  const float* W4  = (const float*)d_in[14];
  const float* b4  = (const float*)d_in[15];
  const float* g4  = (const float*)d_in[16];
  const float* be4 = (const float*)d_in[17];
  const float* W5  = (const float*)d_in[18];
  const float* b5  = (const float*)d_in[19];

  const bool big = ws_size >= NEED_BYTES;
  ushort_t* xh1 = nullptr;
  ushort_t* xh2 = nullptr;
  double* dbase;
  if (big) {
    xh1 = (ushort_t*)d_ws;
    xh2 = xh1 + NTOT;
    dbase = (double*)(xh2 + NTOT);
  } else {
    dbase = (double*)d_ws;
  }
  double* P0 = dbase;
  double* P1 = P0 + P_CNT;
  double* P2 = P1 + P_CNT;
  double* lossAcc = P2 + P_CNT;
  uint_t* cnt = (uint_t*)(lossAcc + 1);
  float* derived = (float*)(lossAcc + 2);

  const dim3 blk(256);
  const dim3 gA(16, 192);
  const dim3 gD(16, 96);

  if (big) {
    pass1_kernel<true><<<gA, blk, 0, stream>>>(x1, x2, xh1, xh2, P0, lossAcc, cnt);
    stats_fold_kernel<<<24, blk, 0, stream>>>(P0, W1, b1, g1, be1, derived, 0);
    pass2_kernel<true><<<gA, blk, 0, stream>>>(x1, x2, xh1, xh2, derived, P1);
    stats_fold_kernel<<<24, blk, 0, stream>>>(P1, W2, b2, g2, be2, derived, 12);
    pass3_kernel<true><<<gA, blk, 0, stream>>>(x1, x2, xh1, xh2, derived, P2);
    stats34_kernel<<<24, blk, 0, stream>>>(P2, W3, b3, g3, be3, W4, b4, g4, be4,
                                           derived);
    pass4_kernel<true><<<gD, blk, 0, stream>>>(x1, x2, xh1, xh2, W5, b5, derived,
                                               lossAcc, cnt, (float*)d_out);
  } else {
    pass1_kernel<false><<<gA, blk, 0, stream>>>(x1, x2, nullptr, nullptr, P0,
                                                lossAcc, cnt);
    stats_fold_kernel<<<24, blk, 0, stream>>>(P0, W1, b1, g1, be1, derived, 0);
    pass2_kernel<false><<<gA, blk, 0, stream>>>(x1, x2, nullptr, nullptr, derived,
                                                P1);
    stats_fold_kernel<<<24, blk, 0, stream>>>(P1, W2, b2, g2, be2, derived, 12);
    pass3_kernel<false><<<gA, blk, 0, stream>>>(x1, x2, nullptr, nullptr, derived,
                                                P2);
    stats34_kernel<<<24, blk, 0, stream>>>(P2, W3, b3, g3, be3, W4, b4, g4, be4,
                                           derived);
    pass4_kernel<false><<<gD, blk, 0, stream>>>(x1, x2, nullptr, nullptr, W5, b5,
                                                derived, lossAcc, cnt,
                                                (float*)d_out);
  }
}